// Round 19
// baseline (192.173 us; speedup 1.0000x reference)
//
#include <hip/hip_runtime.h>
#include <hip/hip_bf16.h>
#include <stdint.h>

#define IN_F 2048
#define OUT_F 128
#define KD 32
#define NR 256
#define OC 2176          // IN_F + OUT_F
#define OD 4096          // OUT_F * KD (T row stride)
#define THRESH 32.0f
#define KSN 16           // k-slices of 128
#define OPN (1024 * 256) // elems per Pp partial

typedef __bf16 bf16x8 __attribute__((ext_vector_type(8)));
typedef __bf16 bf16x4 __attribute__((ext_vector_type(4)));
typedef float  f32x4  __attribute__((ext_vector_type(4)));
typedef uint16_t u16x8 __attribute__((ext_vector_type(8)));

// ---------------------------------------------------------------------------
// Butterfly-FWHT: 8 Walsh projections (masks 0,1,2,4,8,16,3,24) of v[32].
// ---------------------------------------------------------------------------
__device__ __forceinline__ void bfly8(const float v[32], float pr[8]) {
    float s1[16], d1[16];
    #pragma unroll
    for (int e = 0; e < 16; ++e) { s1[e] = v[2*e] + v[2*e+1]; d1[e] = v[2*e] - v[2*e+1]; }
    float s2[8], d2[8];
    #pragma unroll
    for (int e = 0; e < 8; ++e)  { s2[e] = s1[2*e] + s1[2*e+1]; d2[e] = s1[2*e] - s1[2*e+1]; }
    float s3[4], d3[4];
    #pragma unroll
    for (int e = 0; e < 4; ++e)  { s3[e] = s2[2*e] + s2[2*e+1]; d3[e] = s2[2*e] - s2[2*e+1]; }
    float s4[2], d4[2];
    #pragma unroll
    for (int e = 0; e < 2; ++e)  { s4[e] = s3[2*e] + s3[2*e+1]; d4[e] = s3[2*e] - s3[2*e+1]; }
    pr[0] = s4[0] + s4[1];
    { float s = 0.f;
      #pragma unroll
      for (int e = 0; e < 16; ++e) s += d1[e];
      pr[1] = s; }
    { float s = 0.f;
      #pragma unroll
      for (int e = 0; e < 8; ++e) s += d2[e];
      pr[2] = s; }
    pr[3] = (d3[0] + d3[1]) + (d3[2] + d3[3]);
    pr[4] = d4[0] + d4[1];
    pr[5] = s4[0] - s4[1];
    { float s = 0.f;
      #pragma unroll
      for (int g = 0; g < 8; ++g) s += d1[2*g] - d1[2*g+1];
      pr[6] = s; }
    pr[7] = s3[0] - s3[1] - s3[2] + s3[3];
}

// ---------------------------------------------------------------------------
// Mono kernel: producer (tproj+sgemm+x-copy, block b) -> local 16-block
// handoff via per-fo counters -> consumer (screen for f=b>>2, jq=b&3).
// Consumer's needed producer group fo = (b>>2)>>2 = b>>4 = its OWN group.
// grid 512, 256 thr, launch_bounds(256,2) + 51 KB LDS -> all co-resident.
// ---------------------------------------------------------------------------
__global__ __launch_bounds__(256, 2) void mono_kernel(const float* __restrict__ x,
                                                      const float* __restrict__ Tm,
                                                      float* __restrict__ out,
                                                      __bf16* __restrict__ Pp,
                                                      uint32_t* __restrict__ cnt) {
    __shared__ __bf16 Bs[32][136];       // Tproj [o'][k], pad 8
    __shared__ __bf16 As[2][4][257][8];  // x A-frag dbuf, fg-dim padded (bank fix)
    __shared__ float P8s[256][8];
    __shared__ float part[4][64];

    const int tid  = threadIdx.x;
    const int lane = tid & 63;
    const int wid  = tid >> 6;
    const int fr   = lane & 15, fg = lane >> 4;
    const int bid  = blockIdx.x;
    const int ks   = bid & 15;
    const int fo   = bid >> 4;           // f-group of 4 (also consumer's need)
    const int k0   = ks * 128;

    // ======== producer: x -> out copy (4 KB per block) ========
    {
        const int row = bid >> 1;
        const int off = (bid & 1) * 1024 + tid * 4;
        float4 v = *reinterpret_cast<const float4*>(&x[row * IN_F + off]);
        *reinterpret_cast<float4*>(&out[row * OC + off]) = v;
    }

    // x chunk-0 prefetch
    float4 xs[8];
    const int kslot = tid & 7;
    const int nrow8 = tid >> 3;
    #pragma unroll
    for (int p = 0; p < 8; ++p)
        xs[p] = *reinterpret_cast<const float4*>(&x[(p * 32 + nrow8) * IN_F + k0 + kslot * 4]);

    // ======== producer: tproj, both rounds' loads issued up front ========
    {
        const int fl = tid & 3;
        const int kl = tid >> 2;         // 0..63; round 1 = kl + 64, same fl
        const float* src0 = Tm + (size_t)(k0 + kl) * OD + (fo * 4 + fl) * KD;
        const float* src1 = src0 + (size_t)64 * OD;

        float va[32], vb[32];
        #pragma unroll
        for (int q = 0; q < 8; ++q) {
            f32x4 w = *reinterpret_cast<const f32x4*>(src0 + q * 4);
            va[q*4] = w[0]; va[q*4+1] = w[1]; va[q*4+2] = w[2]; va[q*4+3] = w[3];
        }
        #pragma unroll
        for (int q = 0; q < 8; ++q) {
            f32x4 w = *reinterpret_cast<const f32x4*>(src1 + q * 4);
            vb[q*4] = w[0]; vb[q*4+1] = w[1]; vb[q*4+2] = w[2]; vb[q*4+3] = w[3];
        }

        float pra[8], prb[8];
        bfly8(va, pra);
        bfly8(vb, prb);

        // bank-conflict-free write order: p = (pp + fl*2) & 7
        #pragma unroll
        for (int pp = 0; pp < 8; ++pp) {
            const int p = (pp + fl * 2) & 7;
            Bs[fl * 8 + p][kl] = (__bf16)pra[p];
        }
        #pragma unroll
        for (int pp = 0; pp < 8; ++pp) {
            const int p = (pp + fl * 2) & 7;
            Bs[fl * 8 + p][kl + 64] = (__bf16)prb[p];
        }
    }

    // write x chunk 0 into As[0]
    #pragma unroll
    for (int p = 0; p < 8; ++p) {
        bf16x4 b = { (__bf16)xs[p].x, (__bf16)xs[p].y, (__bf16)xs[p].z, (__bf16)xs[p].w };
        *reinterpret_cast<bf16x4*>(&As[0][kslot >> 1][p * 32 + nrow8][(kslot & 1) * 4]) = b;
    }
    __syncthreads();

    // ======== producer: MFMA loop (4 chunks of 32 k) ========
    f32x4 acc[4][2] = {};

    #pragma unroll 1
    for (int c = 0; c < 4; ++c) {
        const int buf = c & 1;
        if (c < 3) {
            #pragma unroll
            for (int p = 0; p < 8; ++p)
                xs[p] = *reinterpret_cast<const float4*>(
                    &x[(p * 32 + nrow8) * IN_F + k0 + (c + 1) * 32 + kslot * 4]);
        }

        bf16x8 bfrag[2];
        #pragma unroll
        for (int oi = 0; oi < 2; ++oi)
            bfrag[oi] = *reinterpret_cast<const bf16x8*>(&Bs[oi * 16 + fr][c * 32 + fg * 8]);
        #pragma unroll
        for (int mi = 0; mi < 4; ++mi) {
            bf16x8 af = *reinterpret_cast<const bf16x8*>(&As[buf][fg][wid * 64 + mi * 16 + fr][0]);
            acc[mi][0] = __builtin_amdgcn_mfma_f32_16x16x32_bf16(af, bfrag[0], acc[mi][0], 0, 0, 0);
            acc[mi][1] = __builtin_amdgcn_mfma_f32_16x16x32_bf16(af, bfrag[1], acc[mi][1], 0, 0, 0);
        }

        if (c < 3) {
            __syncthreads();
            #pragma unroll
            for (int p = 0; p < 8; ++p) {
                bf16x4 b = { (__bf16)xs[p].x, (__bf16)xs[p].y, (__bf16)xs[p].z, (__bf16)xs[p].w };
                *reinterpret_cast<bf16x4*>(&As[buf ^ 1][kslot >> 1][p * 32 + nrow8][(kslot & 1) * 4]) = b;
            }
            __syncthreads();
        }
    }

    // epilogue: bf16 Pp[ks][o'][n]
    {
        __bf16* dst = Pp + (size_t)ks * OPN;
        #pragma unroll
        for (int mi = 0; mi < 4; ++mi) {
            #pragma unroll
            for (int oi = 0; oi < 2; ++oi) {
                const int op = fo * 32 + oi * 16 + fr;
                const int nb = wid * 64 + mi * 16 + fg * 4;
                bf16x4 v = { (__bf16)acc[mi][oi][0], (__bf16)acc[mi][oi][1],
                             (__bf16)acc[mi][oi][2], (__bf16)acc[mi][oi][3] };
                *reinterpret_cast<bf16x4*>(&dst[(size_t)op * NR + nb]) = v;
            }
        }
    }

    // ======== handoff: release own slab, wait for own fo-group (16) ========
    __threadfence();
    __syncthreads();
    if (tid == 0)
        __hip_atomic_fetch_add(&cnt[fo], 1u, __ATOMIC_RELEASE, __HIP_MEMORY_SCOPE_AGENT);

    if (tid == 0) {
        while (__hip_atomic_load(&cnt[fo], __ATOMIC_ACQUIRE, __HIP_MEMORY_SCOPE_AGENT) < 16u)
            __builtin_amdgcn_s_sleep(8);
    }
    __syncthreads();
    __threadfence();

    // ======== consumer: screen for f = bid>>2, jq = bid&3 ========
    {
        const int f  = bid >> 2;
        const int jq = bid & 3;
        const int j  = jq * 64 + lane;

        // stage merged projections (16 bf16 partials, vectorized)
        {
            const int p  = tid >> 5;
            const int n0 = (tid & 31) * 8;
            const uint16_t* base = reinterpret_cast<const uint16_t*>(Pp)
                                 + (size_t)(f * 8 + p) * NR + n0;
            float a[8] = {};
            #pragma unroll
            for (int kk = 0; kk < KSN; ++kk) {
                u16x8 v = *reinterpret_cast<const u16x8*>(base + (size_t)kk * OPN);
                #pragma unroll
                for (int e = 0; e < 8; ++e)
                    a[e] += __builtin_bit_cast(float, (uint32_t)v[e] << 16);
            }
            #pragma unroll
            for (int e = 0; e < 8; ++e)
                P8s[n0 + e][p] = a[e];
        }
        __syncthreads();

        const f32x4 qj0 = *reinterpret_cast<const f32x4*>(&P8s[j][0]);
        const f32x4 qj1 = *reinterpret_cast<const f32x4*>(&P8s[j][4]);

        float acc2 = 0.f;
        const int i0 = wid * 64;
        #pragma unroll 2
        for (int ii = 0; ii < 64; ++ii) {
            const int i = i0 + ii;
            f32x4 r0 = *reinterpret_cast<const f32x4*>(&P8s[i][0]);
            f32x4 r1 = *reinterpret_cast<const f32x4*>(&P8s[i][4]);
            f32x4 d0 = r0 - qj0;
            f32x4 d1 = r1 - qj1;
            float m0 = fmaxf(fmaxf(fabsf(d0[0]), fabsf(d0[1])), fabsf(d0[2]));
            float m1 = fmaxf(fmaxf(fabsf(d0[3]), fabsf(d1[0])), fabsf(d1[1]));
            float m2 = fmaxf(fabsf(d1[2]), fabsf(d1[3]));
            const float mx = fmaxf(fmaxf(m0, m1), m2);

            const bool ok = (mx < THRESH) && (i != j);
            if (__builtin_expect(__any(ok), 0)) {
                if (ok) {
                    f32x4 ad[8] = {};
                    const float* xi = x + (size_t)i * IN_F;
                    const float* xj = x + (size_t)j * IN_F;
                    for (int k = 0; k < IN_F; ++k) {
                        const float dk = xi[k] - xj[k];
                        const float* tr = Tm + (size_t)k * OD + f * KD;
                        #pragma unroll
                        for (int q = 0; q < 8; ++q) {
                            f32x4 tv = *reinterpret_cast<const f32x4*>(tr + q * 4);
                            ad[q] += dk * tv;
                        }
                    }
                    float norm = 0.f;
                    #pragma unroll
                    for (int q = 0; q < 8; ++q)
                        norm += fabsf(ad[q][0]) + fabsf(ad[q][1])
                              + fabsf(ad[q][2]) + fabsf(ad[q][3]);
                    acc2 += __expf(-norm);
                }
            }
        }

        if (wid == jq) acc2 += 1.0f;     // diagonal exp(0)=1, exact

        part[wid][lane] = acc2;
        __syncthreads();
        if (tid < 64) {
            float s = part[0][tid] + part[1][tid] + part[2][tid] + part[3][tid];
            out[(jq * 64 + tid) * OC + IN_F + f] = s;
        }
    }
}

extern "C" void kernel_launch(void* const* d_in, const int* in_sizes, int n_in,
                              void* d_out, int out_size, void* d_ws, size_t ws_size,
                              hipStream_t stream) {
    const float* x  = (const float*)d_in[0];   // [256, 2048] f32
    const float* Tm = (const float*)d_in[1];   // [2048, 4096] f32
    float* out = (float*)d_out;                // [256, 2176] f32
    char*  ws  = (char*)d_ws;

    uint32_t* cnt = (uint32_t*)ws;             // 32 counters (zeroed per call)
    __bf16*   Pp  = (__bf16*)(ws + 1024);      // 8 MB: 16 bf16 o'-major partials

    hipMemsetAsync(cnt, 0, 128, stream);
    mono_kernel<<<dim3(512), 256, 0, stream>>>(x, Tm, out, Pp, cnt);
}

// Round 20
// 38.127 us; speedup vs baseline: 5.0403x; 5.0403x over previous
//
#include <hip/hip_runtime.h>
#include <hip/hip_bf16.h>
#include <stdint.h>

#define IN_F 2048
#define OUT_F 128
#define KD 32
#define NR 256
#define OC 2176          // IN_F + OUT_F
#define OD 4096          // OUT_F * KD (T row stride)
#define THRESH 32.0f
#define KSN 16           // k-slices of 128
#define OPN (1024 * 256) // elems per Pp partial

typedef __bf16 bf16x8 __attribute__((ext_vector_type(8)));
typedef __bf16 bf16x4 __attribute__((ext_vector_type(4)));
typedef float  f32x4  __attribute__((ext_vector_type(4)));
typedef uint16_t u16x8 __attribute__((ext_vector_type(8)));

// ---------------------------------------------------------------------------
// Butterfly-FWHT: 8 Walsh projections (masks 0,1,2,4,8,16,3,24) of v[32].
// ---------------------------------------------------------------------------
__device__ __forceinline__ void bfly8(const float v[32], float pr[8]) {
    float s1[16], d1[16];
    #pragma unroll
    for (int e = 0; e < 16; ++e) { s1[e] = v[2*e] + v[2*e+1]; d1[e] = v[2*e] - v[2*e+1]; }
    float s2[8], d2[8];
    #pragma unroll
    for (int e = 0; e < 8; ++e)  { s2[e] = s1[2*e] + s1[2*e+1]; d2[e] = s1[2*e] - s1[2*e+1]; }
    float s3[4], d3[4];
    #pragma unroll
    for (int e = 0; e < 4; ++e)  { s3[e] = s2[2*e] + s2[2*e+1]; d3[e] = s2[2*e] - s2[2*e+1]; }
    float s4[2], d4[2];
    #pragma unroll
    for (int e = 0; e < 2; ++e)  { s4[e] = s3[2*e] + s3[2*e+1]; d4[e] = s3[2*e] - s3[2*e+1]; }
    pr[0] = s4[0] + s4[1];
    { float s = 0.f;
      #pragma unroll
      for (int e = 0; e < 16; ++e) s += d1[e];
      pr[1] = s; }
    { float s = 0.f;
      #pragma unroll
      for (int e = 0; e < 8; ++e) s += d2[e];
      pr[2] = s; }
    pr[3] = (d3[0] + d3[1]) + (d3[2] + d3[3]);
    pr[4] = d4[0] + d4[1];
    pr[5] = s4[0] - s4[1];
    { float s = 0.f;
      #pragma unroll
      for (int g = 0; g < 8; ++g) s += d1[2*g] - d1[2*g+1];
      pr[6] = s; }
    pr[7] = s3[0] - s3[1] - s3[2] + s3[3];
}

// ---------------------------------------------------------------------------
// K1: fused tproj + sgemm + x-copy. Grid 1024 = (16 ks x 64 fo-of-2f),
// 4 blocks/CU (16 waves/CU). Per block: T slab 128k x 2f read ONCE ->
// butterfly -> Bs[16 o'][136]; ONE syncthreads; then 4 MFMA chunks with
// A-frags loaded DIRECTLY from x (L2-hot, 2 float4 + cvt per frag) -- no
// As LDS, no per-chunk barriers. Epilogue bf16 Pp[ks][o'][n].
// ---------------------------------------------------------------------------
__global__ __launch_bounds__(256, 4) void fused_kernel(const float* __restrict__ x,
                                                       const float* __restrict__ Tm,
                                                       float* __restrict__ out,
                                                       __bf16* __restrict__ Pp) {
    __shared__ __bf16 Bs[16][136];       // Tproj [o'_local][k_local], pad 8

    const int tid  = threadIdx.x;
    const int lane = tid & 63;
    const int wid  = tid >> 6;
    const int fr   = lane & 15, fg = lane >> 4;
    const int bid  = blockIdx.x;
    const int ks   = bid & 15;
    const int fo   = bid >> 4;           // 0..63: f-group of 2
    const int k0   = ks * 128;

    // ---- x -> out copy (blocks 0..511 cover all rows)
    if (bid < 512) {
        const int row = bid >> 1;
        const int off = (bid & 1) * 1024 + tid * 4;
        float4 v = *reinterpret_cast<const float4*>(&x[row * IN_F + off]);
        *reinterpret_cast<float4*>(&out[row * OC + off]) = v;
    }

    // ---- tproj: 1 (k,f) pair per thread; 8 b128 loads then butterfly
    {
        const int fl = tid & 1;
        const int kl = tid >> 1;         // 0..127
        const float* src = Tm + (size_t)(k0 + kl) * OD + (fo * 2 + fl) * KD;

        float v[32];
        #pragma unroll
        for (int q = 0; q < 8; ++q) {
            f32x4 w = *reinterpret_cast<const f32x4*>(src + q * 4);
            v[q*4] = w[0]; v[q*4+1] = w[1]; v[q*4+2] = w[2]; v[q*4+3] = w[3];
        }

        float pr[8];
        bfly8(v, pr);

        // rotated write order: fl-pair lands 16 banks apart (2-way = free)
        #pragma unroll
        for (int pp = 0; pp < 8; ++pp) {
            const int p = (pp + fl * 4) & 7;
            Bs[fl * 8 + p][kl] = (__bf16)pr[p];
        }
    }
    __syncthreads();

    // ---- MFMA: 4 chunks of 32 k; wave tile 64 n x 16 o'; A direct from x
    f32x4 acc[4] = {};

    #pragma unroll
    for (int c = 0; c < 4; ++c) {
        const bf16x8 bfrag = *reinterpret_cast<const bf16x8*>(&Bs[fr][c * 32 + fg * 8]);
        #pragma unroll
        for (int mi = 0; mi < 4; ++mi) {
            const int n = wid * 64 + mi * 16 + fr;
            const float* ap = &x[(size_t)n * IN_F + k0 + c * 32 + fg * 8];
            float4 u0 = *reinterpret_cast<const float4*>(ap);
            float4 u1 = *reinterpret_cast<const float4*>(ap + 4);
            bf16x8 af = { (__bf16)u0.x, (__bf16)u0.y, (__bf16)u0.z, (__bf16)u0.w,
                          (__bf16)u1.x, (__bf16)u1.y, (__bf16)u1.z, (__bf16)u1.w };
            acc[mi] = __builtin_amdgcn_mfma_f32_16x16x32_bf16(af, bfrag, acc[mi], 0, 0, 0);
        }
    }

    // ---- epilogue: Pp[ks][o' = fo*16 + fr][n = wid*64 + mi*16 + fg*4 + r]
    {
        __bf16* dst = Pp + (size_t)ks * OPN;
        const int op = fo * 16 + fr;
        #pragma unroll
        for (int mi = 0; mi < 4; ++mi) {
            const int nb = wid * 64 + mi * 16 + fg * 4;
            bf16x4 v = { (__bf16)acc[mi][0], (__bf16)acc[mi][1],
                         (__bf16)acc[mi][2], (__bf16)acc[mi][3] };
            *reinterpret_cast<bf16x4*>(&dst[(size_t)op * NR + nb]) = v;
        }
    }
}

// ---------------------------------------------------------------------------
// K2 (verbatim R17): screen. Staged merged projections (16 bf16 partials,
// vectorized u16x8); drop pair when max_p |dproj| > 32 (sound: L1 >=
// |dproj|; margins leave dropped terms <= 256*e^-17 ~ 1e-5 << 0.099).
// Rare survivor -> exact norm on the fly from x and T.
// ---------------------------------------------------------------------------
__global__ __launch_bounds__(256, 2) void screen_kernel(const __bf16* __restrict__ Pp,
                                                        const float* __restrict__ x,
                                                        const float* __restrict__ Tm,
                                                        float* __restrict__ out) {
    __shared__ float P8s[256][8];
    __shared__ float part[4][64];

    const int f    = blockIdx.x;
    const int jq   = blockIdx.y;
    const int tid  = threadIdx.x;
    const int lane = tid & 63;
    const int wid  = tid >> 6;
    const int j    = jq * 64 + lane;

    {
        const int p  = tid >> 5;
        const int n0 = (tid & 31) * 8;
        const uint16_t* base = reinterpret_cast<const uint16_t*>(Pp)
                             + (size_t)(f * 8 + p) * NR + n0;
        float a[8] = {};
        #pragma unroll
        for (int ks = 0; ks < KSN; ++ks) {
            u16x8 v = *reinterpret_cast<const u16x8*>(base + (size_t)ks * OPN);
            #pragma unroll
            for (int e = 0; e < 8; ++e)
                a[e] += __builtin_bit_cast(float, (uint32_t)v[e] << 16);
        }
        #pragma unroll
        for (int e = 0; e < 8; ++e)
            P8s[n0 + e][p] = a[e];
    }
    __syncthreads();

    const f32x4 qj0 = *reinterpret_cast<const f32x4*>(&P8s[j][0]);
    const f32x4 qj1 = *reinterpret_cast<const f32x4*>(&P8s[j][4]);

    float acc = 0.f;
    const int i0 = wid * 64;
    #pragma unroll 2
    for (int ii = 0; ii < 64; ++ii) {
        const int i = i0 + ii;
        f32x4 r0 = *reinterpret_cast<const f32x4*>(&P8s[i][0]);
        f32x4 r1 = *reinterpret_cast<const f32x4*>(&P8s[i][4]);
        f32x4 d0 = r0 - qj0;
        f32x4 d1 = r1 - qj1;
        float m0 = fmaxf(fmaxf(fabsf(d0[0]), fabsf(d0[1])), fabsf(d0[2]));
        float m1 = fmaxf(fmaxf(fabsf(d0[3]), fabsf(d1[0])), fabsf(d1[1]));
        float m2 = fmaxf(fabsf(d1[2]), fabsf(d1[3]));
        const float mx = fmaxf(fmaxf(m0, m1), m2);

        const bool ok = (mx < THRESH) && (i != j);
        if (__builtin_expect(__any(ok), 0)) {
            if (ok) {
                f32x4 ad[8] = {};
                const float* xi = x + (size_t)i * IN_F;
                const float* xj = x + (size_t)j * IN_F;
                for (int k = 0; k < IN_F; ++k) {
                    const float dk = xi[k] - xj[k];
                    const float* tr = Tm + (size_t)k * OD + f * KD;
                    #pragma unroll
                    for (int q = 0; q < 8; ++q) {
                        f32x4 tv = *reinterpret_cast<const f32x4*>(tr + q * 4);
                        ad[q] += dk * tv;
                    }
                }
                float norm = 0.f;
                #pragma unroll
                for (int q = 0; q < 8; ++q)
                    norm += fabsf(ad[q][0]) + fabsf(ad[q][1])
                          + fabsf(ad[q][2]) + fabsf(ad[q][3]);
                acc += __expf(-norm);
            }
        }
    }

    if (wid == jq) acc += 1.0f;          // diagonal exp(0)=1, exact

    part[wid][lane] = acc;
    __syncthreads();
    if (tid < 64) {
        float s = part[0][tid] + part[1][tid] + part[2][tid] + part[3][tid];
        out[(jq * 64 + tid) * OC + IN_F + f] = s;
    }
}

extern "C" void kernel_launch(void* const* d_in, const int* in_sizes, int n_in,
                              void* d_out, int out_size, void* d_ws, size_t ws_size,
                              hipStream_t stream) {
    const float* x  = (const float*)d_in[0];   // [256, 2048] f32
    const float* Tm = (const float*)d_in[1];   // [2048, 4096] f32
    float* out = (float*)d_out;                // [256, 2176] f32

    __bf16* Pp = (__bf16*)d_ws;                // 8 MB: 16 bf16 o'-major partials

    fused_kernel<<<dim3(1024), 256, 0, stream>>>(x, Tm, out, Pp);
    screen_kernel<<<dim3(128, 4), 256, 0, stream>>>(Pp, x, Tm, out);
}

// Round 21
// 31.466 us; speedup vs baseline: 6.1074x; 1.2117x over previous
//
#include <hip/hip_runtime.h>
#include <hip/hip_bf16.h>
#include <stdint.h>

#define IN_F 2048
#define OUT_F 128
#define KD 32
#define NR 256
#define OC 2176          // IN_F + OUT_F
#define OD 4096          // OUT_F * KD (T row stride)
#define THRESH 32.0f
#define KSN 16           // k-slices of 128
#define OPN (1024 * 256) // elems per Pp partial

typedef __bf16 bf16x8 __attribute__((ext_vector_type(8)));
typedef __bf16 bf16x4 __attribute__((ext_vector_type(4)));
typedef float  f32x4  __attribute__((ext_vector_type(4)));
typedef uint16_t u16x8 __attribute__((ext_vector_type(8)));

// ---------------------------------------------------------------------------
// K1 (verbatim R17, best-measured): fused tproj + sgemm + x-copy.
// Block = (ks in [0,16), fo in [0,32)). T slab read once -> butterfly ->
// Tproj LDS; x staged inline as MFMA A-frags (dbuf); bf16 Pp partials.
// ---------------------------------------------------------------------------
__global__ __launch_bounds__(256, 2) void fused_kernel(const float* __restrict__ x,
                                                       const float* __restrict__ Tm,
                                                       float* __restrict__ out,
                                                       __bf16* __restrict__ Pp) {
    __shared__ __bf16 Bs[32][136];       // Tproj slab [o'_local][k_local], pad 8
    __shared__ __bf16 As[2][4][256][8];  // x A-frag dbuf (32 KB)

    const int tid  = threadIdx.x;
    const int lane = tid & 63;
    const int wid  = tid >> 6;
    const int fr   = lane & 15, fg = lane >> 4;
    const int bid  = blockIdx.x;
    const int ks   = bid & 15;
    const int fo   = bid >> 4;           // f-group of 4
    const int k0   = ks * 128;

    // ---- x -> out copy (block covers 4 KB: row bid>>1, half bid&1)
    {
        const int row = bid >> 1;
        const int off = (bid & 1) * 1024 + tid * 4;
        float4 v = *reinterpret_cast<const float4*>(&x[row * IN_F + off]);
        *reinterpret_cast<float4*>(&out[row * OC + off]) = v;
    }

    // ---- issue x chunk-0 loads early (latency hides under butterflies)
    float4 xs[8];
    const int kslot = tid & 7;
    const int nrow8 = tid >> 3;          // n = p*32 + nrow8
    #pragma unroll
    for (int p = 0; p < 8; ++p)
        xs[p] = *reinterpret_cast<const float4*>(&x[(p * 32 + nrow8) * IN_F + k0 + kslot * 4]);

    // ---- tproj: 2 (k,f) pairs per thread (sequential; keeps VGPR < 128)
    #pragma unroll 1
    for (int r = 0; r < 2; ++r) {
        const int idx = r * 256 + tid;
        const int fl  = idx & 3;
        const int kl  = idx >> 2;        // 0..127
        const float* src = Tm + (size_t)(k0 + kl) * OD + (fo * 4 + fl) * KD;

        float v[32];
        #pragma unroll
        for (int q = 0; q < 8; ++q) {
            f32x4 w = *reinterpret_cast<const f32x4*>(src + q * 4);
            v[q * 4]     = w[0];
            v[q * 4 + 1] = w[1];
            v[q * 4 + 2] = w[2];
            v[q * 4 + 3] = w[3];
        }

        float s1[16], d1[16];
        #pragma unroll
        for (int e = 0; e < 16; ++e) { s1[e] = v[2*e] + v[2*e+1]; d1[e] = v[2*e] - v[2*e+1]; }
        float s2[8], d2[8];
        #pragma unroll
        for (int e = 0; e < 8; ++e)  { s2[e] = s1[2*e] + s1[2*e+1]; d2[e] = s1[2*e] - s1[2*e+1]; }
        float s3[4], d3[4];
        #pragma unroll
        for (int e = 0; e < 4; ++e)  { s3[e] = s2[2*e] + s2[2*e+1]; d3[e] = s2[2*e] - s2[2*e+1]; }
        float s4[2], d4[2];
        #pragma unroll
        for (int e = 0; e < 2; ++e)  { s4[e] = s3[2*e] + s3[2*e+1]; d4[e] = s3[2*e] - s3[2*e+1]; }
        const float s5 = s4[0] + s4[1];
        const float d5 = s4[0] - s4[1];

        float pr[8];
        pr[0] = s5;
        { float s = 0.f;
          #pragma unroll
          for (int e = 0; e < 16; ++e) s += d1[e];
          pr[1] = s; }
        { float s = 0.f;
          #pragma unroll
          for (int e = 0; e < 8; ++e) s += d2[e];
          pr[2] = s; }
        pr[3] = (d3[0] + d3[1]) + (d3[2] + d3[3]);
        pr[4] = d4[0] + d4[1];
        pr[5] = d5;
        { float s = 0.f;
          #pragma unroll
          for (int g = 0; g < 8; ++g) s += d1[2*g] - d1[2*g+1];
          pr[6] = s; }
        pr[7] = s3[0] - s3[1] - s3[2] + s3[3];

        #pragma unroll
        for (int p = 0; p < 8; ++p)
            Bs[fl * 8 + p][kl] = (__bf16)pr[p];
    }

    // ---- write x chunk 0 into As[0]
    #pragma unroll
    for (int p = 0; p < 8; ++p) {
        bf16x4 b = { (__bf16)xs[p].x, (__bf16)xs[p].y, (__bf16)xs[p].z, (__bf16)xs[p].w };
        *reinterpret_cast<bf16x4*>(&As[0][kslot >> 1][p * 32 + nrow8][(kslot & 1) * 4]) = b;
    }
    __syncthreads();

    // ---- MFMA loop: 4 chunks of 32 k; acc[mi][oi], wave owns 64 n x 32 o'
    f32x4 acc[4][2] = {};

    #pragma unroll 1
    for (int c = 0; c < 4; ++c) {
        const int buf = c & 1;
        if (c < 3) {
            #pragma unroll
            for (int p = 0; p < 8; ++p)
                xs[p] = *reinterpret_cast<const float4*>(
                    &x[(p * 32 + nrow8) * IN_F + k0 + (c + 1) * 32 + kslot * 4]);
        }

        bf16x8 bfrag[2];
        #pragma unroll
        for (int oi = 0; oi < 2; ++oi)
            bfrag[oi] = *reinterpret_cast<const bf16x8*>(&Bs[oi * 16 + fr][c * 32 + fg * 8]);
        #pragma unroll
        for (int mi = 0; mi < 4; ++mi) {
            bf16x8 af = *reinterpret_cast<const bf16x8*>(&As[buf][fg][wid * 64 + mi * 16 + fr][0]);
            acc[mi][0] = __builtin_amdgcn_mfma_f32_16x16x32_bf16(af, bfrag[0], acc[mi][0], 0, 0, 0);
            acc[mi][1] = __builtin_amdgcn_mfma_f32_16x16x32_bf16(af, bfrag[1], acc[mi][1], 0, 0, 0);
        }

        if (c < 3) {
            __syncthreads();             // all waves done with As[buf^1] readers
            #pragma unroll
            for (int p = 0; p < 8; ++p) {
                bf16x4 b = { (__bf16)xs[p].x, (__bf16)xs[p].y, (__bf16)xs[p].z, (__bf16)xs[p].w };
                *reinterpret_cast<bf16x4*>(&As[buf ^ 1][kslot >> 1][p * 32 + nrow8][(kslot & 1) * 4]) = b;
            }
            __syncthreads();
        }
    }

    // ---- epilogue: Pp[ks][o' = fo*32 + oi*16 + fr][n = wid*64+mi*16+fg*4+r] bf16
    __bf16* dst = Pp + (size_t)ks * OPN;
    #pragma unroll
    for (int mi = 0; mi < 4; ++mi) {
        #pragma unroll
        for (int oi = 0; oi < 2; ++oi) {
            const int op = fo * 32 + oi * 16 + fr;
            const int nb = wid * 64 + mi * 16 + fg * 4;
            bf16x4 v = { (__bf16)acc[mi][oi][0], (__bf16)acc[mi][oi][1],
                         (__bf16)acc[mi][oi][2], (__bf16)acc[mi][oi][3] };
            *reinterpret_cast<bf16x4*>(&dst[(size_t)op * NR + nb]) = v;
        }
    }
}

// ---------------------------------------------------------------------------
// K2 (R21): screen with REGISTER-resident i-side. After staging P8s, each
// lane holds its wave's 64 i-rows' projections (P8s[i0+lane][0..8) -> 8
// VGPRs); the hot loop fetches the i-row via v_readlane (uniform counter) --
// ZERO LDS traffic in the loop (R18 measured the old loop LDS-pipe-bound).
// Screen math and exact fallback unchanged (drop when max_p |dproj| > 32).
// ---------------------------------------------------------------------------
__device__ __forceinline__ float rdlane(float v, int l) {
    return __builtin_bit_cast(float, __builtin_amdgcn_readlane(__builtin_bit_cast(int, v), l));
}

__global__ __launch_bounds__(256, 2) void screen_kernel(const __bf16* __restrict__ Pp,
                                                        const float* __restrict__ x,
                                                        const float* __restrict__ Tm,
                                                        float* __restrict__ out) {
    __shared__ float P8s[256][8];
    __shared__ float part[4][64];

    const int f    = blockIdx.x;
    const int jq   = blockIdx.y;
    const int tid  = threadIdx.x;
    const int lane = tid & 63;
    const int wid  = tid >> 6;
    const int j    = jq * 64 + lane;

    // stage merged projections (16 bf16 partials, vectorized u16x8)
    {
        const int p  = tid >> 5;
        const int n0 = (tid & 31) * 8;
        const uint16_t* base = reinterpret_cast<const uint16_t*>(Pp)
                             + (size_t)(f * 8 + p) * NR + n0;
        float a[8] = {};
        #pragma unroll
        for (int ks = 0; ks < KSN; ++ks) {
            u16x8 v = *reinterpret_cast<const u16x8*>(base + (size_t)ks * OPN);
            #pragma unroll
            for (int e = 0; e < 8; ++e)
                a[e] += __builtin_bit_cast(float, (uint32_t)v[e] << 16);
        }
        #pragma unroll
        for (int e = 0; e < 8; ++e)
            P8s[n0 + e][p] = a[e];
    }
    __syncthreads();

    const f32x4 qj0 = *reinterpret_cast<const f32x4*>(&P8s[j][0]);
    const f32x4 qj1 = *reinterpret_cast<const f32x4*>(&P8s[j][4]);

    const int i0 = wid * 64;
    // lane-resident i-side: lane l holds row i0+l (one-time LDS read)
    const f32x4 my0 = *reinterpret_cast<const f32x4*>(&P8s[i0 + lane][0]);
    const f32x4 my1 = *reinterpret_cast<const f32x4*>(&P8s[i0 + lane][4]);

    float acc = 0.f;
    #pragma unroll 4
    for (int ii = 0; ii < 64; ++ii) {
        const int i = i0 + ii;
        const float d0 = fabsf(rdlane(my0[0], ii) - qj0[0]);
        const float d1 = fabsf(rdlane(my0[1], ii) - qj0[1]);
        const float d2 = fabsf(rdlane(my0[2], ii) - qj0[2]);
        const float d3 = fabsf(rdlane(my0[3], ii) - qj0[3]);
        const float d4 = fabsf(rdlane(my1[0], ii) - qj1[0]);
        const float d5 = fabsf(rdlane(my1[1], ii) - qj1[1]);
        const float d6 = fabsf(rdlane(my1[2], ii) - qj1[2]);
        const float d7 = fabsf(rdlane(my1[3], ii) - qj1[3]);
        const float mx = fmaxf(fmaxf(fmaxf(d0, d1), fmaxf(d2, d3)),
                               fmaxf(fmaxf(d4, d5), fmaxf(d6, d7)));

        const bool ok = (mx < THRESH) && (i != j);
        if (__builtin_expect(__any(ok), 0)) {
            if (ok) {
                f32x4 ad[8] = {};
                const float* xi = x + (size_t)i * IN_F;
                const float* xj = x + (size_t)j * IN_F;
                for (int k = 0; k < IN_F; ++k) {
                    const float dk = xi[k] - xj[k];
                    const float* tr = Tm + (size_t)k * OD + f * KD;
                    #pragma unroll
                    for (int q = 0; q < 8; ++q) {
                        f32x4 tv = *reinterpret_cast<const f32x4*>(tr + q * 4);
                        ad[q] += dk * tv;
                    }
                }
                float norm = 0.f;
                #pragma unroll
                for (int q = 0; q < 8; ++q)
                    norm += fabsf(ad[q][0]) + fabsf(ad[q][1])
                          + fabsf(ad[q][2]) + fabsf(ad[q][3]);
                acc += __expf(-norm);
            }
        }
    }

    if (wid == jq) acc += 1.0f;          // diagonal exp(0)=1, exact

    part[wid][lane] = acc;
    __syncthreads();
    if (tid < 64) {
        float s = part[0][tid] + part[1][tid] + part[2][tid] + part[3][tid];
        out[(jq * 64 + tid) * OC + IN_F + f] = s;
    }
}

extern "C" void kernel_launch(void* const* d_in, const int* in_sizes, int n_in,
                              void* d_out, int out_size, void* d_ws, size_t ws_size,
                              hipStream_t stream) {
    const float* x  = (const float*)d_in[0];   // [256, 2048] f32
    const float* Tm = (const float*)d_in[1];   // [2048, 4096] f32
    float* out = (float*)d_out;                // [256, 2176] f32

    __bf16* Pp = (__bf16*)d_ws;                // 8 MB: 16 bf16 o'-major partials

    fused_kernel<<<dim3(512), 256, 0, stream>>>(x, Tm, out, Pp);
    screen_kernel<<<dim3(128, 4), 256, 0, stream>>>(Pp, x, Tm, out);
}